// Round 3
// baseline (650.407 us; speedup 1.0000x reference)
//
#include <hip/hip_runtime.h>

typedef _Float16 f16;
typedef _Float16 f16x8 __attribute__((ext_vector_type(8)));
typedef float f32x16 __attribute__((ext_vector_type(16)));

// ---------------------------------------------------------------------------
// async 16B global->LDS copy (global_load_lds_dwordx4)
// LDS side is HW-forced to wave-uniform-base + lane*16 (m104/m108).
// ---------------------------------------------------------------------------
__device__ __forceinline__ void g2lds16(const void* g, void* l) {
    __builtin_amdgcn_global_load_lds(
        (const __attribute__((address_space(1))) void*)g,
        (__attribute__((address_space(3))) void*)l, 16, 0, 0);
}

// ---------------------------------------------------------------------------
// Pack Wq|Wk|Wv -> f16 Wall[2048][1024], biases -> ball[2048] fp32
// ---------------------------------------------------------------------------
__global__ __launch_bounds__(256)
void prep_w(const float* __restrict__ Wq, const float* __restrict__ bq,
            const float* __restrict__ Wk, const float* __restrict__ bk,
            const float* __restrict__ Wv, const float* __restrict__ bv,
            f16* __restrict__ Wall, float* __restrict__ ball)
{
    const int idx = blockIdx.x * 256 + threadIdx.x;   // 0 .. 2^21-1
    const int o = idx >> 10;
    const int c = idx & 1023;
    float w;
    if (o < 512)        w = Wq[idx];
    else if (o < 1024)  w = Wk[idx - 512 * 1024];
    else                w = Wv[idx - 1024 * 1024];
    Wall[idx] = (f16)w;
    if (c == 0)
        ball[o] = (o < 512) ? bq[o] : (o < 1024) ? bk[o - 512] : bv[o - 1024];
}

// ---------------------------------------------------------------------------
// x [B,C,N] fp32 -> xT [B,N,C] f16.  64x64 tile: float4 loads (256B rows),
// f16x8 (16B) stores. LDS pad 65 -> conflict-free.
// ---------------------------------------------------------------------------
__global__ __launch_bounds__(256)
void transpose_cast(const float* __restrict__ x, f16* __restrict__ xT)
{
    __shared__ float t[64][65];
    const int b  = blockIdx.z;
    const int c0 = blockIdx.y << 6;
    const int n0 = blockIdx.x << 6;
    const int tid = threadIdx.x;
    const float* xb = x + (unsigned long long)b * (1024ull * 1024ull);

    {
        const int cl = tid >> 4;          // 0..15
        const int n4 = (tid & 15) << 2;   // 0..60
#pragma unroll
        for (int i = 0; i < 64; i += 16) {
            const float4 v = *(const float4*)(xb + (unsigned long long)(c0 + cl + i) * 1024ull + (n0 + n4));
            t[cl + i][n4 + 0] = v.x; t[cl + i][n4 + 1] = v.y;
            t[cl + i][n4 + 2] = v.z; t[cl + i][n4 + 3] = v.w;
        }
    }
    __syncthreads();
    {
        f16* ob = xT + (unsigned long long)b * (1024ull * 1024ull);
        const int nl = tid >> 3;          // 0..31
        const int c8 = (tid & 7) << 3;    // 0..56
#pragma unroll
        for (int i = 0; i < 64; i += 32) {
            f16x8 h;
#pragma unroll
            for (int j = 0; j < 8; ++j) h[j] = (f16)t[c8 + j][nl + i];
            *(f16x8*)(ob + (unsigned long long)(n0 + nl + i) * 1024ull + (c0 + c8)) = h;
        }
    }
}

// ---------------------------------------------------------------------------
// NT GEMM: C[m,n] = sum_k A[m,k]*B[n,k]  (both row-major, contract last dim)
// 128x128 tile, BK=64, 4 waves 2x2, 64x64/wave, mfma_f32_32x32x16_f16 (2x2).
// LDS: flat [128][64] f16, XOR-swizzled on the GLOBAL address side.
// SWZ=1 (GEMM1): XCD-pinned supertiles (see prior notes; 3MB < 4MB L2).
// SWZ=2 (GEMM3): 1-D grid 2048; pin (batch, bn-half) units to XCDs:
//   per unit working set = A (V, 2MB) + B-half (P, 1MB) = 3MB < 4MB L2.
// EPI 0: +bias[n] store f16. EPI 1: store fp32. EPI 2: +=Xres store fp32.
// ---------------------------------------------------------------------------
template <int EPI, int LDA, int LDB, int K, int LDO,
          long long SA, long long SB, long long SO, int SWZ>
__global__ __launch_bounds__(256, 4)
void gemm_nt(const f16* __restrict__ A, const f16* __restrict__ Bm,
             const float* __restrict__ bias,
             f16* __restrict__ Oh, float* __restrict__ Of,
             const float* __restrict__ Xres)
{
    __shared__ f16 As[128 * 64];
    __shared__ f16 Bs[128 * 64];

    const int tid  = threadIdx.x;
    const int wave = tid >> 6;
    const int lane = tid & 63;
    const int l31  = lane & 31;
    const int half = lane >> 5;
    const int wr   = (wave >> 1) << 6;   // wave row offset: 0 / 64
    const int wc   = (wave & 1) << 6;    // wave col offset: 0 / 64

    int bm, bn, bz = blockIdx.z;
    if (SWZ == 1) {
        const int xcd   = blockIdx.x & 7;
        const int local = blockIdx.x >> 3;    // 0..511
        const int stl   = local >> 5;         // 0..15 sequential per XCD
        const int sub   = local & 31;
        const int bng   = xcd & 1;            // bn-half owned by this XCD
        const int g4    = stl * 4 + (xcd >> 1);  // 0..63 bm-group-of-4
        bm = (g4 * 4 + (sub & 3)) << 7;
        bn = (bng * 8 + (sub >> 2)) << 7;
    } else if (SWZ == 2) {
        const int xcd   = blockIdx.x & 7;
        const int local = blockIdx.x >> 3;    // 0..255
        const int unit  = local >> 5;         // 0..7 sequential per XCD
        const int wi    = local & 31;         // 8 bm x 4 bn-within-half
        const int pp    = unit * 8 + xcd;     // 0..63 (batch, half) pairs
        bz = pp >> 1;
        const int bh = pp & 1;
        bm = (wi & 7) << 7;
        bn = ((bh << 2) + (wi >> 3)) << 7;
    } else {
        bm = blockIdx.x << 7;
        bn = blockIdx.y << 7;
    }

    const f16* Ab = A  + (unsigned long long)bz * (unsigned long long)SA;
    const f16* Bb = Bm + (unsigned long long)bz * (unsigned long long)SB;

    // staging: lane -> row rb + (l>>3); global k-group XOR-swizzled
    const int srow = lane >> 3;                    // 0..7
    const int scol = (((lane & 7) ^ srow) << 3);   // swizzled f16 col offset

    f32x16 acc[2][2] = {};

    for (int k0 = 0; k0 < K; k0 += 64) {
        __syncthreads();
#pragma unroll
        for (int t = 0; t < 4; ++t) {
            const int rb = t * 32 + wave * 8;     // wave-uniform
            g2lds16(Ab + (unsigned long long)(bm + rb + srow) * LDA + (k0 + scol),
                    As + rb * 64 + lane * 8);
            g2lds16(Bb + (unsigned long long)(bn + rb + srow) * LDB + (k0 + scol),
                    Bs + rb * 64 + lane * 8);
        }
        __syncthreads();

#pragma unroll
        for (int ks = 0; ks < 4; ++ks) {
            const int kg = ks * 2 + half;         // k-group 0..7
            f16x8 af[2], bf[2];
#pragma unroll
            for (int i = 0; i < 2; ++i) {
                const int ra = wr + i * 32 + l31;
                af[i] = *(const f16x8*)(As + ra * 64 + ((kg ^ (ra & 7)) << 3));
                const int rbn = wc + i * 32 + l31;
                bf[i] = *(const f16x8*)(Bs + rbn * 64 + ((kg ^ (rbn & 7)) << 3));
            }
#pragma unroll
            for (int mi = 0; mi < 2; ++mi)
#pragma unroll
                for (int ni = 0; ni < 2; ++ni)
                    acc[mi][ni] = __builtin_amdgcn_mfma_f32_32x32x16_f16(
                        af[mi], bf[ni], acc[mi][ni], 0, 0, 0);
        }
    }

    // epilogue: 32x32 C/D layout col=lane&31, row=(r&3)+8*(r>>2)+4*half
#pragma unroll
    for (int mi = 0; mi < 2; ++mi) {
#pragma unroll
        for (int ni = 0; ni < 2; ++ni) {
            const int col = bn + wc + ni * 32 + l31;
            float bc = 0.0f;
            if (EPI == 0) bc = bias[col];
#pragma unroll
            for (int r = 0; r < 16; ++r) {
                const int row = bm + wr + mi * 32 + (r & 3) + 8 * (r >> 2) + 4 * half;
                const float val = acc[mi][ni][r];
                if (EPI == 0) {
                    Oh[(unsigned long long)row * LDO + col] = (f16)(val + bc);
                } else if (EPI == 1) {
                    Of[(unsigned long long)bz * (unsigned long long)SO +
                       (unsigned long long)row * LDO + col] = val;
                } else {
                    const unsigned long long off =
                        (unsigned long long)bz * (unsigned long long)SO +
                        (unsigned long long)row * LDO + col;
                    Of[off] = val + Xres[off];
                }
            }
        }
    }
}

// ---------------------------------------------------------------------------
// Fused scores + row-softmax:  P[b, j, key] = softmax_key( Q[b,j,:] . K[b,key,:] )
// One block = one batch x 32 q-rows x ALL 1024 keys. 8 waves, wave w owns
// keys [128w, 128w+128). Q [32][512] f16 staged once (slot-XOR swizzle);
// K staged per 32-d chunk as [512 superrows][8 slots of 16B], XOR ^(R&7)
// (4-way read conflict, same class as gemm_nt). Softmax in-register:
// butterfly over l31 + 8-wave LDS reduce (same math as old softmax_rows).
// P repacked through LDS (reusing Ks) -> fully coalesced 16B stores.
// XCD-pinned: batch = xcd*4 + ..., so K+Q (2MB/batch) stay L2-resident.
// ---------------------------------------------------------------------------
__global__ __launch_bounds__(512)
void qk_softmax(const f16* __restrict__ QKV, f16* __restrict__ P)
{
    __shared__ f16 Qs[32 * 512];        // 32KB
    __shared__ f16 Ks[512 * 64];        // 64KB; reused as P-tile [32][1024]
    __shared__ float redm[8][2][16];
    __shared__ float reds[8][2][16];

    const int tid  = threadIdx.x;
    const int wave = tid >> 6;
    const int lane = tid & 63;
    const int l31  = lane & 31;
    const int half = lane >> 5;

    const int xcd   = blockIdx.x & 7;
    const int local = blockIdx.x >> 3;      // 0..127
    const int batch = xcd * 4 + (local >> 5);
    const int jt    = local & 31;
    const int j0    = jt << 5;

    const f16* Qb = QKV + (unsigned long long)batch * (1024ull * 2048ull);
    const f16* Kb = Qb + 512;

    // stage Q [32][512] once; LDS slot s holds global slot s^(row&7)
#pragma unroll
    for (int i = 0; i < 4; ++i) {
        const int row = wave * 4 + i;
        g2lds16(Qb + (unsigned long long)(j0 + row) * 2048ull + ((lane ^ (row & 7)) << 3),
                Qs + row * 512 + lane * 8);
    }

    f32x16 acc[4] = {};
    const int wkey = wave << 7;             // 128 keys per wave

    for (int d0 = 0; d0 < 512; d0 += 32) {
        __syncthreads();
        // stage K chunk [1024 keys][32 d] as [512 superrows][8 slots], XOR ^(R&7)
#pragma unroll
        for (int t = 0; t < 8; ++t) {
            const int rb  = wave * 64 + t * 8;       // superrow base (mult of 8)
            const int R   = rb + (lane >> 3);
            const int p   = (lane & 7) ^ (R & 7);    // source position
            const int key = (R << 1) + (p >> 2);
            const int slt = p & 3;
            g2lds16(Kb + (unsigned long long)key * 2048ull + d0 + (slt << 3),
                    Ks + rb * 64 + lane * 8);
        }
        __syncthreads();
#pragma unroll
        for (int ks = 0; ks < 2; ++ks) {
            const int sl = ks * 2 + half;            // slot within d-step, 0..3
            const int gs = (d0 >> 3) + sl;           // global 8-f16 slot in Q row
            const f16x8 af = *(const f16x8*)(Qs + l31 * 512 + ((gs ^ (l31 & 7)) << 3));
#pragma unroll
            for (int ni = 0; ni < 4; ++ni) {
                const int key = wkey + ni * 32 + l31;
                const int R   = key >> 1;
                const int p   = ((key & 1) << 2) + sl;
                const f16x8 bf = *(const f16x8*)(Ks + R * 64 + ((p ^ (R & 7)) << 3));
                acc[ni] = __builtin_amdgcn_mfma_f32_32x32x16_f16(af, bf, acc[ni], 0, 0, 0);
            }
        }
    }

    // ---- row softmax over 1024 keys ----
    float mx[16];
#pragma unroll
    for (int r = 0; r < 16; ++r) {
        float m = fmaxf(fmaxf(acc[0][r], acc[1][r]), fmaxf(acc[2][r], acc[3][r]));
#pragma unroll
        for (int off = 16; off; off >>= 1)
            m = fmaxf(m, __shfl_xor(m, off, 64));
        mx[r] = m;
    }
    if (l31 == 0) {
#pragma unroll
        for (int r = 0; r < 16; ++r) redm[wave][half][r] = mx[r];
    }
    __syncthreads();
#pragma unroll
    for (int r = 0; r < 16; ++r) {
        float m = redm[0][half][r];
#pragma unroll
        for (int w = 1; w < 8; ++w) m = fmaxf(m, redm[w][half][r]);
        mx[r] = m;
    }

    float sm[16];
#pragma unroll
    for (int r = 0; r < 16; ++r) sm[r] = 0.0f;
#pragma unroll
    for (int ni = 0; ni < 4; ++ni)
#pragma unroll
        for (int r = 0; r < 16; ++r) {
            const float e = __expf(acc[ni][r] - mx[r]);
            acc[ni][r] = e;
            sm[r] += e;
        }
#pragma unroll
    for (int r = 0; r < 16; ++r) {
#pragma unroll
        for (int off = 16; off; off >>= 1)
            sm[r] += __shfl_xor(sm[r], off, 64);
    }
    if (l31 == 0) {
#pragma unroll
        for (int r = 0; r < 16; ++r) reds[wave][half][r] = sm[r];
    }
    __syncthreads();
#pragma unroll
    for (int r = 0; r < 16; ++r) {
        float s = reds[0][half][r];
#pragma unroll
        for (int w = 1; w < 8; ++w) s += reds[w][half][r];
        sm[r] = 1.0f / s;
    }

    // ---- write P tile through LDS (reuse Ks; all K reads are done) ----
    f16* Pt = Ks;
#pragma unroll
    for (int ni = 0; ni < 4; ++ni)
#pragma unroll
        for (int r = 0; r < 16; ++r) {
            const int row = (r & 3) + 8 * (r >> 2) + 4 * half;
            const int key = wkey + ni * 32 + l31;
            Pt[row * 1024 + key] = (f16)(acc[ni][r] * sm[r]);
        }
    __syncthreads();

    // tile is 32 contiguous rows -> flat contiguous 64KB copy, 16B per lane
    f16* Pg = P + ((unsigned long long)batch * 1024ull + j0) * 1024ull;
#pragma unroll
    for (int i = 0; i < 8; ++i)
        *(f16x8*)(Pg + i * 4096 + tid * 8) = *(const f16x8*)(Pt + i * 4096 + tid * 8);
}

// ---------------------------------------------------------------------------
extern "C" void kernel_launch(void* const* d_in, const int* in_sizes, int n_in,
                              void* d_out, int out_size, void* d_ws, size_t ws_size,
                              hipStream_t stream)
{
    const float* x  = (const float*)d_in[0];
    const float* Wq = (const float*)d_in[1];
    const float* bq = (const float*)d_in[2];
    const float* Wk = (const float*)d_in[3];
    const float* bk = (const float*)d_in[4];
    const float* Wv = (const float*)d_in[5];
    const float* bv = (const float*)d_in[6];
    float* out = (float*)d_out;

    // workspace layout (all 16B-aligned)
    f16*   xT   = (f16*)d_ws;                               //  64 MB: [32,1024(N),1024(C)]
    f16*   Wall = xT + 32ull * 1024 * 1024;                 //   4 MB: [2048,1024]
    float* ball = (float*)(Wall + 2048ull * 1024);          //   8 KB
    f16*   QKV  = (f16*)(ball + 2048);                      // 128 MB: [32,1024, q|k|v 2048]
    f16*   P    = QKV + 64ull * 1024 * 1024;                //  64 MB: [32,1024,1024]

    prep_w<<<8192, 256, 0, stream>>>(Wq, bq, Wk, bk, Wv, bv, Wall, ball);
    transpose_cast<<<dim3(16, 16, 32), 256, 0, stream>>>(x, xT);

    // QKV projection: [32768,1024] x [2048,1024]^T -> [32768,2048], +bias, f16
    gemm_nt<0, 1024, 1024, 1024, 2048, 0ll, 0ll, 0ll, 1>
        <<<dim3(4096, 1, 1), 256, 0, stream>>>(
        xT, Wall, ball, QKV, nullptr, nullptr);

    // fused scores + softmax: per batch q[1024,512] x k'[1024,512]^T -> P f16
    qk_softmax<<<dim3(1024, 1, 1), 512, 0, stream>>>(QKV, P);

    // out: per batch  v[1024,1024] x attn[1024,1024]^T  (+x residual) -> fp32
    gemm_nt<2, 2048, 1024, 1024, 1024, 1024ll * 2048, 1024ll * 1024, 1024ll * 1024, 2>
        <<<dim3(2048, 1, 1), 256, 0, stream>>>(
        QKV + 1024, P, nullptr, nullptr, out, x);
}

// Round 4
// 600.162 us; speedup vs baseline: 1.0837x; 1.0837x over previous
//
#include <hip/hip_runtime.h>

typedef _Float16 f16;
typedef _Float16 f16x8 __attribute__((ext_vector_type(8)));
typedef float f32x16 __attribute__((ext_vector_type(16)));

// ---------------------------------------------------------------------------
// async 16B global->LDS copy (global_load_lds_dwordx4)
// LDS side is HW-forced to wave-uniform-base + lane*16 (m104/m108).
// ---------------------------------------------------------------------------
__device__ __forceinline__ void g2lds16(const void* g, void* l) {
    __builtin_amdgcn_global_load_lds(
        (const __attribute__((address_space(1))) void*)g,
        (__attribute__((address_space(3))) void*)l, 16, 0, 0);
}

// ---------------------------------------------------------------------------
// Pack Wq|Wk|Wv -> f16 Wall[2048][1024], biases -> ball[2048] fp32
// ---------------------------------------------------------------------------
__global__ __launch_bounds__(256)
void prep_w(const float* __restrict__ Wq, const float* __restrict__ bq,
            const float* __restrict__ Wk, const float* __restrict__ bk,
            const float* __restrict__ Wv, const float* __restrict__ bv,
            f16* __restrict__ Wall, float* __restrict__ ball)
{
    const int idx = blockIdx.x * 256 + threadIdx.x;   // 0 .. 2^21-1
    const int o = idx >> 10;
    const int c = idx & 1023;
    float w;
    if (o < 512)        w = Wq[idx];
    else if (o < 1024)  w = Wk[idx - 512 * 1024];
    else                w = Wv[idx - 1024 * 1024];
    Wall[idx] = (f16)w;
    if (c == 0)
        ball[o] = (o < 512) ? bq[o] : (o < 1024) ? bk[o - 512] : bv[o - 1024];
}

// ---------------------------------------------------------------------------
// x [B,C,N] fp32 -> xT [B,N,C] f16.  64x64 tile: float4 loads (256B rows),
// f16x8 (16B) stores. LDS pad 65 -> conflict-free.
// ---------------------------------------------------------------------------
__global__ __launch_bounds__(256)
void transpose_cast(const float* __restrict__ x, f16* __restrict__ xT)
{
    __shared__ float t[64][65];
    const int b  = blockIdx.z;
    const int c0 = blockIdx.y << 6;
    const int n0 = blockIdx.x << 6;
    const int tid = threadIdx.x;
    const float* xb = x + (unsigned long long)b * (1024ull * 1024ull);

    {
        const int cl = tid >> 4;          // 0..15
        const int n4 = (tid & 15) << 2;   // 0..60
#pragma unroll
        for (int i = 0; i < 64; i += 16) {
            const float4 v = *(const float4*)(xb + (unsigned long long)(c0 + cl + i) * 1024ull + (n0 + n4));
            t[cl + i][n4 + 0] = v.x; t[cl + i][n4 + 1] = v.y;
            t[cl + i][n4 + 2] = v.z; t[cl + i][n4 + 3] = v.w;
        }
    }
    __syncthreads();
    {
        f16* ob = xT + (unsigned long long)b * (1024ull * 1024ull);
        const int nl = tid >> 3;          // 0..31
        const int c8 = (tid & 7) << 3;    // 0..56
#pragma unroll
        for (int i = 0; i < 64; i += 32) {
            f16x8 h;
#pragma unroll
            for (int j = 0; j < 8; ++j) h[j] = (f16)t[c8 + j][nl + i];
            *(f16x8*)(ob + (unsigned long long)(n0 + nl + i) * 1024ull + (c0 + c8)) = h;
        }
    }
}

// ---------------------------------------------------------------------------
// NT GEMM: C[m,n] = sum_k A[m,k]*B[n,k]  (both row-major, contract last dim)
// 128x128 tile, BK=64, 4 waves 2x2, 64x64/wave, mfma_f32_32x32x16_f16 (2x2).
// LDS: flat [128][64] f16, XOR-swizzled on the GLOBAL address side.
// SWZ=1 (GEMM1): XCD-pinned supertiles (see prior notes; 3MB < 4MB L2).
// SWZ=2 (GEMM3): 1-D grid 2048; pin (batch, bn-half) units to XCDs:
//   per unit working set = A (V, 2MB) + B-half (P, 1MB) = 3MB < 4MB L2.
// EPI 0: +bias[n] store f16. EPI 1: store fp32. EPI 2: +=Xres store fp32.
// ---------------------------------------------------------------------------
template <int EPI, int LDA, int LDB, int K, int LDO,
          long long SA, long long SB, long long SO, int SWZ>
__global__ __launch_bounds__(256, 4)
void gemm_nt(const f16* __restrict__ A, const f16* __restrict__ Bm,
             const float* __restrict__ bias,
             f16* __restrict__ Oh, float* __restrict__ Of,
             const float* __restrict__ Xres)
{
    __shared__ f16 As[128 * 64];
    __shared__ f16 Bs[128 * 64];

    const int tid  = threadIdx.x;
    const int wave = tid >> 6;
    const int lane = tid & 63;
    const int l31  = lane & 31;
    const int half = lane >> 5;
    const int wr   = (wave >> 1) << 6;   // wave row offset: 0 / 64
    const int wc   = (wave & 1) << 6;    // wave col offset: 0 / 64

    int bm, bn, bz = blockIdx.z;
    if (SWZ == 1) {
        const int xcd   = blockIdx.x & 7;
        const int local = blockIdx.x >> 3;    // 0..511
        const int stl   = local >> 5;         // 0..15 sequential per XCD
        const int sub   = local & 31;
        const int bng   = xcd & 1;            // bn-half owned by this XCD
        const int g4    = stl * 4 + (xcd >> 1);  // 0..63 bm-group-of-4
        bm = (g4 * 4 + (sub & 3)) << 7;
        bn = (bng * 8 + (sub >> 2)) << 7;
    } else if (SWZ == 2) {
        const int xcd   = blockIdx.x & 7;
        const int local = blockIdx.x >> 3;    // 0..255
        const int unit  = local >> 5;         // 0..7 sequential per XCD
        const int wi    = local & 31;         // 8 bm x 4 bn-within-half
        const int pp    = unit * 8 + xcd;     // 0..63 (batch, half) pairs
        bz = pp >> 1;
        const int bh = pp & 1;
        bm = (wi & 7) << 7;
        bn = ((bh << 2) + (wi >> 3)) << 7;
    } else {
        bm = blockIdx.x << 7;
        bn = blockIdx.y << 7;
    }

    const f16* Ab = A  + (unsigned long long)bz * (unsigned long long)SA;
    const f16* Bb = Bm + (unsigned long long)bz * (unsigned long long)SB;

    // staging: lane -> row rb + (l>>3); global k-group XOR-swizzled
    const int srow = lane >> 3;                    // 0..7
    const int scol = (((lane & 7) ^ srow) << 3);   // swizzled f16 col offset

    f32x16 acc[2][2] = {};

    for (int k0 = 0; k0 < K; k0 += 64) {
        __syncthreads();
#pragma unroll
        for (int t = 0; t < 4; ++t) {
            const int rb = t * 32 + wave * 8;     // wave-uniform
            g2lds16(Ab + (unsigned long long)(bm + rb + srow) * LDA + (k0 + scol),
                    As + rb * 64 + lane * 8);
            g2lds16(Bb + (unsigned long long)(bn + rb + srow) * LDB + (k0 + scol),
                    Bs + rb * 64 + lane * 8);
        }
        __syncthreads();

#pragma unroll
        for (int ks = 0; ks < 4; ++ks) {
            const int kg = ks * 2 + half;         // k-group 0..7
            f16x8 af[2], bf[2];
#pragma unroll
            for (int i = 0; i < 2; ++i) {
                const int ra = wr + i * 32 + l31;
                af[i] = *(const f16x8*)(As + ra * 64 + ((kg ^ (ra & 7)) << 3));
                const int rbn = wc + i * 32 + l31;
                bf[i] = *(const f16x8*)(Bs + rbn * 64 + ((kg ^ (rbn & 7)) << 3));
            }
#pragma unroll
            for (int mi = 0; mi < 2; ++mi)
#pragma unroll
                for (int ni = 0; ni < 2; ++ni)
                    acc[mi][ni] = __builtin_amdgcn_mfma_f32_32x32x16_f16(
                        af[mi], bf[ni], acc[mi][ni], 0, 0, 0);
        }
    }

    // epilogue: 32x32 C/D layout col=lane&31, row=(r&3)+8*(r>>2)+4*half
#pragma unroll
    for (int mi = 0; mi < 2; ++mi) {
#pragma unroll
        for (int ni = 0; ni < 2; ++ni) {
            const int col = bn + wc + ni * 32 + l31;
            float bc = 0.0f;
            if (EPI == 0) bc = bias[col];
#pragma unroll
            for (int r = 0; r < 16; ++r) {
                const int row = bm + wr + mi * 32 + (r & 3) + 8 * (r >> 2) + 4 * half;
                const float val = acc[mi][ni][r];
                if (EPI == 0) {
                    Oh[(unsigned long long)row * LDO + col] = (f16)(val + bc);
                } else if (EPI == 1) {
                    Of[(unsigned long long)bz * (unsigned long long)SO +
                       (unsigned long long)row * LDO + col] = val;
                } else {
                    const unsigned long long off =
                        (unsigned long long)bz * (unsigned long long)SO +
                        (unsigned long long)row * LDO + col;
                    Of[off] = val + Xres[off];
                }
            }
        }
    }
}

// ---------------------------------------------------------------------------
// Fused scores + row-softmax v2:  P[b,j,key] = softmax_key(Q[b,j,:].K[b,key,:])
// Block = one batch x 64 q-rows x 1024 keys; 8 waves, wave w owns keys
// [128w,128w+128).  KEY POINT: wave w stages ONLY its own keys -> the K
// pipeline is barrier-free.  Per 16-d chunk: issue stage(t+1) into dbuf,
// s_waitcnt vmcnt(4) (counted, T4) + sched_barrier(0) (rule 18), then
// 2 af + 4 bf ds_read_b128 + 8 MFMA (setprio-wrapped, T5).  32 chunks.
// Q [64][512] staged once (slot-XOR ^(row&7)); K slot-XOR s^=((s>>3)&1)
// applied as the SAME involution on stage-source and read side (rule 21).
// LDS 136KB: Qs 64K + Ks dbuf 2x32K + red 8K -> 1 block/CU (8 waves).
// Softmax: butterfly over l31 + 8-wave LDS reduce. P repacked via Ks in
// two 32-row passes -> coalesced 16B stores.
// ---------------------------------------------------------------------------
__global__ __launch_bounds__(512)
void qk_softmax(const f16* __restrict__ QKV, f16* __restrict__ P)
{
    __shared__ f16 Qs[64 * 512];            // 64KB
    __shared__ f16 Ks[2 * 8 * 2048];        // 64KB: [buf][wave][256 16B-slots]
    __shared__ float redm[8][2][2][16];     // 4KB [wave][sub][half][r]
    __shared__ float reds[8][2][2][16];     // 4KB

    const int tid  = threadIdx.x;
    const int wave = tid >> 6;
    const int lane = tid & 63;
    const int l31  = lane & 31;
    const int half = lane >> 5;

    const int xcd   = blockIdx.x & 7;
    const int local = blockIdx.x >> 3;          // 0..63
    const int batch = xcd * 4 + (local >> 4);   // 4 batches per XCD
    const int j0    = (local & 15) << 6;        // 64-row q tile

    const f16* Qb = QKV + (unsigned long long)batch * (1024ull * 2048ull);
    const f16* Kb = Qb + 512;

    // ---- prologue: stage Q[64][512] (slot-XOR per row) + K chunk 0 ----
#pragma unroll
    for (int i = 0; i < 8; ++i) {
        const int row = wave * 8 + i;           // row&7 == i
        g2lds16(Qb + (unsigned long long)(j0 + row) * 2048ull + ((lane ^ i) << 3),
                Qs + row * 512 + lane * 8);
    }
    // per-lane K staging constants: LDS slot (i*64+lane) holds logical slot
    // u = (i*64+lane) ^ bit3 -> lu = lane ^ ((lane>>3)&1)
    const int lu = lane ^ ((lane >> 3) & 1);
    const f16* Kw = Kb + (unsigned long long)(wave * 128 + (lu >> 1)) * 2048ull
                       + ((lu & 1) << 3);
    f16* KsW = Ks + wave * 2048;                // wave-private region (f16)
#pragma unroll
    for (int i = 0; i < 4; ++i)                 // chunk 0 -> buf 0
        g2lds16(Kw + i * (32 * 2048), KsW + i * 512 + lane * 8);

    asm volatile("s_waitcnt vmcnt(0)" ::: "memory");
    __builtin_amdgcn_sched_barrier(0);
    __syncthreads();                            // Q visible to all waves

    // per-lane read constants
    const int r7 = l31 & 7;
    // bf physical slot = ni*64 + sb, sb = (2*l31+half) ^ ((l31>>2)&1)
    const int sb = ((l31 << 1) + half) ^ ((l31 >> 2) & 1);
    const f16* KsR = Ks + wave * 2048 + sb * 8;

    f32x16 acc[2][4] = {};

    for (int tt = 0; tt < 16; ++tt) {
#pragma unroll
        for (int p = 0; p < 2; ++p) {           // buf parity compile-time
            const int t = tt * 2 + p;           // chunk 0..31
            if (t < 31) {
#pragma unroll
                for (int i = 0; i < 4; ++i)     // stage chunk t+1 -> buf p^1
                    g2lds16(Kw + (t + 1) * 16 + i * (32 * 2048),
                            KsW + (p ^ 1) * 16384 + i * 512 + lane * 8);
                asm volatile("s_waitcnt vmcnt(4)" ::: "memory");
            } else {
                asm volatile("s_waitcnt vmcnt(0)" ::: "memory");
            }
            __builtin_amdgcn_sched_barrier(0);

            const int gs = t * 2 + half;        // 8-f16 slot in Q row
            f16x8 af[2];
#pragma unroll
            for (int sub = 0; sub < 2; ++sub)
                af[sub] = *(const f16x8*)(Qs + (sub * 32 + l31) * 512 + ((gs ^ r7) << 3));
            f16x8 bf[4];
#pragma unroll
            for (int ni = 0; ni < 4; ++ni)
                bf[ni] = *(const f16x8*)(KsR + p * 16384 + ni * 512);

            __builtin_amdgcn_s_setprio(1);
#pragma unroll
            for (int sub = 0; sub < 2; ++sub)
#pragma unroll
                for (int ni = 0; ni < 4; ++ni)
                    acc[sub][ni] = __builtin_amdgcn_mfma_f32_32x32x16_f16(
                        af[sub], bf[ni], acc[sub][ni], 0, 0, 0);
            __builtin_amdgcn_s_setprio(0);
        }
    }

    // ---- row softmax over 1024 keys (per sub-tile of 32 rows) ----
    float mx[2][16];
#pragma unroll
    for (int sub = 0; sub < 2; ++sub)
#pragma unroll
        for (int r = 0; r < 16; ++r) {
            float m = fmaxf(fmaxf(acc[sub][0][r], acc[sub][1][r]),
                            fmaxf(acc[sub][2][r], acc[sub][3][r]));
#pragma unroll
            for (int off = 16; off; off >>= 1)
                m = fmaxf(m, __shfl_xor(m, off, 64));
            mx[sub][r] = m;
        }
    if (l31 == 0) {
#pragma unroll
        for (int sub = 0; sub < 2; ++sub)
#pragma unroll
            for (int r = 0; r < 16; ++r) redm[wave][sub][half][r] = mx[sub][r];
    }
    __syncthreads();
#pragma unroll
    for (int sub = 0; sub < 2; ++sub)
#pragma unroll
        for (int r = 0; r < 16; ++r) {
            float m = redm[0][sub][half][r];
#pragma unroll
            for (int w = 1; w < 8; ++w) m = fmaxf(m, redm[w][sub][half][r]);
            mx[sub][r] = m;
        }

    float sm[2][16];
#pragma unroll
    for (int sub = 0; sub < 2; ++sub)
#pragma unroll
        for (int r = 0; r < 16; ++r) sm[sub][r] = 0.0f;
#pragma unroll
    for (int sub = 0; sub < 2; ++sub)
#pragma unroll
        for (int ni = 0; ni < 4; ++ni)
#pragma unroll
            for (int r = 0; r < 16; ++r) {
                const float e = __expf(acc[sub][ni][r] - mx[sub][r]);
                acc[sub][ni][r] = e;
                sm[sub][r] += e;
            }
#pragma unroll
    for (int sub = 0; sub < 2; ++sub)
#pragma unroll
        for (int r = 0; r < 16; ++r) {
#pragma unroll
            for (int off = 16; off; off >>= 1)
                sm[sub][r] += __shfl_xor(sm[sub][r], off, 64);
        }
    if (l31 == 0) {
#pragma unroll
        for (int sub = 0; sub < 2; ++sub)
#pragma unroll
            for (int r = 0; r < 16; ++r) reds[wave][sub][half][r] = sm[sub][r];
    }
    __syncthreads();
#pragma unroll
    for (int sub = 0; sub < 2; ++sub)
#pragma unroll
        for (int r = 0; r < 16; ++r) {
            float s = reds[0][sub][half][r];
#pragma unroll
            for (int w = 1; w < 8; ++w) s += reds[w][sub][half][r];
            sm[sub][r] = 1.0f / s;
        }

    // ---- P writeout via Ks as [32][1024] tile, two 32-row passes ----
    f16* Pt = Ks;
#pragma unroll
    for (int pass = 0; pass < 2; ++pass) {      // unrolled: acc[pass] static
        __syncthreads();                        // Ks free (compute/copy done)
#pragma unroll
        for (int ni = 0; ni < 4; ++ni)
#pragma unroll
            for (int r = 0; r < 16; ++r) {
                const int row = (r & 3) + 8 * (r >> 2) + 4 * half;
                const int key = (wave << 7) + ni * 32 + l31;
                Pt[row * 1024 + key] = (f16)(acc[pass][ni][r] * sm[pass][r]);
            }
        __syncthreads();
        f16* Pg = P + ((unsigned long long)batch * 1024ull + j0 + pass * 32) * 1024ull;
#pragma unroll
        for (int i = 0; i < 8; ++i)
            *(f16x8*)(Pg + i * 4096 + tid * 8) = *(const f16x8*)(Pt + i * 4096 + tid * 8);
    }
}

// ---------------------------------------------------------------------------
extern "C" void kernel_launch(void* const* d_in, const int* in_sizes, int n_in,
                              void* d_out, int out_size, void* d_ws, size_t ws_size,
                              hipStream_t stream)
{
    const float* x  = (const float*)d_in[0];
    const float* Wq = (const float*)d_in[1];
    const float* bq = (const float*)d_in[2];
    const float* Wk = (const float*)d_in[3];
    const float* bk = (const float*)d_in[4];
    const float* Wv = (const float*)d_in[5];
    const float* bv = (const float*)d_in[6];
    float* out = (float*)d_out;

    // workspace layout (all 16B-aligned)
    f16*   xT   = (f16*)d_ws;                               //  64 MB: [32,1024(N),1024(C)]
    f16*   Wall = xT + 32ull * 1024 * 1024;                 //   4 MB: [2048,1024]
    float* ball = (float*)(Wall + 2048ull * 1024);          //   8 KB
    f16*   QKV  = (f16*)(ball + 2048);                      // 128 MB: [32,1024, q|k|v 2048]
    f16*   P    = QKV + 64ull * 1024 * 1024;                //  64 MB: [32,1024,1024]

    prep_w<<<8192, 256, 0, stream>>>(Wq, bq, Wk, bk, Wv, bv, Wall, ball);
    transpose_cast<<<dim3(16, 16, 32), 256, 0, stream>>>(x, xT);

    // QKV projection: [32768,1024] x [2048,1024]^T -> [32768,2048], +bias, f16
    gemm_nt<0, 1024, 1024, 1024, 2048, 0ll, 0ll, 0ll, 1>
        <<<dim3(4096, 1, 1), 256, 0, stream>>>(
        xT, Wall, ball, QKV, nullptr, nullptr);

    // fused scores + softmax: per batch q[1024,512] x k'[1024,512]^T -> P f16
    qk_softmax<<<dim3(512, 1, 1), 512, 0, stream>>>(QKV, P);

    // out: per batch  v[1024,1024] x attn[1024,1024]^T  (+x residual) -> fp32
    gemm_nt<2, 2048, 1024, 1024, 1024, 1024ll * 2048, 1024ll * 1024, 1024ll * 1024, 2>
        <<<dim3(2048, 1, 1), 256, 0, stream>>>(
        QKV + 1024, P, nullptr, nullptr, out, x);
}